// Round 3
// baseline (245.885 us; speedup 1.0000x reference)
//
#include <hip/hip_runtime.h>
#include <stdint.h>

typedef short v8s __attribute__((ext_vector_type(8)));
typedef float v4f __attribute__((ext_vector_type(4)));

#define NPTS 2048
#define BATCH 16
#define KNN 20
#define PAIRS (NPTS * KNN)   // 40960 per batch

// ---------- helpers ----------
__device__ __forceinline__ unsigned bf16pack2(float lo, float hi) {
  unsigned ul = __float_as_uint(lo), uh = __float_as_uint(hi);
  return ((ul + 0x8000u) >> 16) | ((uh + 0x8000u) & 0xffff0000u);
}
__device__ __forceinline__ unsigned pair_h2(unsigned pu, unsigned qu) {
  float pl = __uint_as_float(pu << 16);
  float ph = __uint_as_float(pu & 0xffff0000u);
  float ql = __uint_as_float(qu << 16);
  float qh = __uint_as_float(qu & 0xffff0000u);
  return bf16pack2(fmaxf(pl + ql, 0.f), fmaxf(ph + qh, 0.f));
}
__device__ __forceinline__ unsigned long long sx64(unsigned long long v, int m) {
  unsigned lo = __shfl_xor((unsigned)v, m);
  unsigned hi = __shfl_xor((unsigned)(v >> 32), m);
  return ((unsigned long long)hi << 32) | lo;
}

// ---------- K0: fold M2a = W2*W1a, M2b = W2*(W1b-W1a); zero H ----------
__global__ void prep_kernel(const float* __restrict__ W1, const float* __restrict__ W2,
                            float* __restrict__ M2a, float* __restrict__ M2b,
                            int* __restrict__ H) {
  if (blockIdx.x == 0 && threadIdx.x < 128) {
    int o = threadIdx.x;
    float a0 = 0, a1 = 0, a2 = 0, b0 = 0, b1 = 0, b2 = 0;
    for (int i = 0; i < 64; ++i) {
      float w2 = W2[o * 64 + i];
      const float* w1r = W1 + i * 6;
      a0 += w2 * w1r[0]; a1 += w2 * w1r[1]; a2 += w2 * w1r[2];
      b0 += w2 * (w1r[3] - w1r[0]); b1 += w2 * (w1r[4] - w1r[1]); b2 += w2 * (w1r[5] - w1r[2]);
    }
    M2a[o * 3 + 0] = a0; M2a[o * 3 + 1] = a1; M2a[o * 3 + 2] = a2;
    M2b[o * 3 + 0] = b0; M2b[o * 3 + 1] = b1; M2b[o * 3 + 2] = b2;
  }
  int g = blockIdx.x * 128 + threadIdx.x;
  if (g < BATCH * 256) H[g] = 0;
}

// ---------- K1: p[b][j][o] = M2a[o]·x_j ; q likewise (bf16, packed pairs) ----------
__global__ __launch_bounds__(64) void pq_kernel(const float* __restrict__ x,
                                                const float* __restrict__ M2a,
                                                const float* __restrict__ M2b,
                                                unsigned short* __restrict__ p,
                                                unsigned short* __restrict__ q) {
  int b = blockIdx.x >> 6;
  int j0 = (blockIdx.x & 63) << 5;
  int t = threadIdx.x;                 // 0..63 -> channels 2t, 2t+1
  int o0 = t * 2;
  float a00 = M2a[o0 * 3 + 0], a01 = M2a[o0 * 3 + 1], a02 = M2a[o0 * 3 + 2];
  float a10 = M2a[o0 * 3 + 3], a11 = M2a[o0 * 3 + 4], a12 = M2a[o0 * 3 + 5];
  float b00 = M2b[o0 * 3 + 0], b01 = M2b[o0 * 3 + 1], b02 = M2b[o0 * 3 + 2];
  float b10 = M2b[o0 * 3 + 3], b11 = M2b[o0 * 3 + 4], b12 = M2b[o0 * 3 + 5];
  const float* xb = x + b * 3 * NPTS;
  unsigned* pw = (unsigned*)p;
  unsigned* qw = (unsigned*)q;
  for (int jj = 0; jj < 32; ++jj) {
    int j = j0 + jj;
    float x0 = xb[j], x1 = xb[NPTS + j], x2 = xb[2 * NPTS + j];
    float p0 = a00 * x0 + a01 * x1 + a02 * x2;
    float p1 = a10 * x0 + a11 * x1 + a12 * x2;
    float q0 = b00 * x0 + b01 * x1 + b02 * x2;
    float q1 = b10 * x0 + b11 * x1 + b12 * x2;
    size_t base = ((size_t)(b * NPTS + j)) * 64 + t;   // dword index
    pw[base] = bf16pack2(p0, p1);
    qw[base] = bf16pack2(q0, q1);
  }
}

// ---------- K2: exact 20-NN, one wave per query ----------
// R2: dl[32] register array spilled to scratch (~536MB traffic = the whole
// 83us) -> recompute distances in pass 2.
// R3: R2 FAILED (absmax 93.5): pass-1 vs pass-2 compile with different FMA
// contraction, so recomputed d can exceed tau by ulps -> <20 candidates ->
// sentinel index 0xffffffff -> garbage gather. Fix: inflate tau by 2^-18
// relative (sum of 3 nonneg products differs by <= ~4 ulp across any
// contraction; 64-ulp margin is 16x that). Extra shell admits ~0 candidates,
// ranking itself uses pass-2 values consistently.
__global__ __launch_bounds__(256) void knn_kernel(const float* __restrict__ x,
                                                  int* __restrict__ idxOut) {
  __shared__ float4 pts[NPTS];                  // 32 KB
  __shared__ unsigned sd[4][128];               // candidate dist bits
  __shared__ int sm[4][128];                    // candidate indices
  int b = blockIdx.x >> 9;
  int qb = (blockIdx.x & 511) << 2;
  const float* xb = x + b * 3 * NPTS;
  for (int i = threadIdx.x; i < NPTS; i += 256) {
    pts[i] = make_float4(xb[i], xb[NPTS + i], xb[2 * NPTS + i], 0.f);
  }
  __syncthreads();
  int wid = threadIdx.x >> 6, lane = threadIdx.x & 63;
  int qn = qb + wid;
  float4 Q = pts[qn];

  // pass 1: per-lane min distance over its 32 points (no storage)
  float mymin = 1e30f;
#pragma unroll
  for (int s = 0; s < 32; ++s) {
    float4 P = pts[s * 64 + lane];
    float dx = P.x - Q.x, dy = P.y - Q.y, dz = P.z - Q.z;
    float d = dx * dx + dy * dy + dz * dz;
    mymin = fminf(mymin, d);
  }
  // bitonic sort 64 lane-minima ascending -> tau = 20th smallest.
  // Upper bound proof: the 20 smallest lane-minima are 20 actual distances in
  // distinct lanes, all <= tau => at least 20 distances <= tau => d_(20) <= tau.
  float v = mymin;
  for (int k = 2; k <= 64; k <<= 1) {
    for (int j = k >> 1; j > 0; j >>= 1) {
      float o = __shfl_xor(v, j);
      bool low = (lane & j) == 0;
      bool up = (lane & k) == 0;
      v = (low == up) ? fminf(v, o) : fmaxf(v, o);
    }
  }
  float tau = __shfl(v, 19);
  tau = tau * (1.0f + 3.8e-6f);   // +2^-18 rel: covers cross-pass FMA-contraction ulps

  // pass 2: recompute distances, ballot-compact all candidates with d <= tau
  int base = 0;
#pragma unroll
  for (int s = 0; s < 32; ++s) {
    float4 P = pts[s * 64 + lane];
    float dx = P.x - Q.x, dy = P.y - Q.y, dz = P.z - Q.z;
    float d = dx * dx + dy * dy + dz * dz;
    bool take = d <= tau;
    unsigned long long mb = __ballot(take);
    if (mb) {
      if (take) {
        int pos = base + __popcll(mb & ((1ull << lane) - 1ull));
        if (pos < 128) {
          sd[wid][pos] = __float_as_uint(d);
          sm[wid][pos] = s * 64 + lane;
        }
      }
      base += __popcll(mb);
    }
  }
  int nc = base < 128 ? base : 128;
  __syncthreads();

  // final select: bitonic sort up to 128 keys (2 per lane), key = (distbits<<32)|m
  // (dist asc, then index asc -> matches jax top_k tie-breaking)
  unsigned long long k0 = (lane < nc)
      ? ((((unsigned long long)sd[wid][lane]) << 32) | (unsigned)sm[wid][lane]) : ~0ull;
  unsigned long long k1 = (lane + 64 < nc)
      ? ((((unsigned long long)sd[wid][lane + 64]) << 32) | (unsigned)sm[wid][lane + 64]) : ~0ull;
  for (int k = 2; k <= 128; k <<= 1) {
    for (int j = k >> 1; j > 0; j >>= 1) {
      if (j == 64) {  // cross-reg, same lane (only k==128, ascending)
        unsigned long long mn = k0 < k1 ? k0 : k1;
        unsigned long long mx = k0 < k1 ? k1 : k0;
        k0 = mn; k1 = mx;
      } else {
        unsigned long long o0 = sx64(k0, j), o1 = sx64(k1, j);
        bool low = (lane & j) == 0;
        bool up0 = ((lane & k) == 0);
        bool up1 = (((lane + 64) & k) == 0);
        k0 = ((low == up0) == (k0 < o0)) ? k0 : o0;
        k1 = ((low == up1) == (k1 < o1)) ? k1 : o1;
      }
    }
  }
  if (lane < KNN) {
    idxOut[((size_t)b * NPTS + qn) * KNN + lane] = (int)(k0 & 0xffffffffu);
  }
}

// ---------- K3: h3 = relu(W3 · relu(p_j+q_n)) via MFMA, fused max-reduce ----------
__global__ __launch_bounds__(256, 2) void gemm_max_kernel(
    const unsigned short* __restrict__ p, const unsigned short* __restrict__ q,
    const int* __restrict__ idx, const float* __restrict__ W3, int* __restrict__ H) {
  __shared__ __align__(16) unsigned short h2s[2][16 * 136];  // 8704 B double-buffered tile

  int b = blockIdx.x & 15;
  int w = blockIdx.x >> 4;  // 0..47
  int t = threadIdx.x;
  int lane = t & 63, wid = t >> 6;
  int r16 = lane & 15, quad = lane >> 4;

  // Preload all B fragments (W3^T rows, bf16) into registers: 4 ntiles x 4 ksteps
  v8s bfr[4][4];
#pragma unroll
  for (int ntl = 0; ntl < 4; ++ntl) {
#pragma unroll
    for (int kk = 0; kk < 4; ++kk) {
      int n = (wid * 4 + ntl) * 16 + r16;
      const float* src = W3 + n * 128 + kk * 32 + quad * 8;
      v8s f;
#pragma unroll
      for (int jj = 0; jj < 8; ++jj)
        f[jj] = (short)((__float_as_uint(src[jj]) + 0x8000u) >> 16);
      bfr[ntl][kk] = f;
    }
  }

  const unsigned short* pB = p + (size_t)b * NPTS * 128;
  const unsigned short* qB = q + (size_t)b * NPTS * 128;
  const int* idxB = idx + (size_t)b * PAIRS;

  int pm = t >> 4;        // pair-in-tile 0..15
  int cseg = t & 15;      // 8-channel segment

  float vmx[4] = {0.f, 0.f, 0.f, 0.f};
  int buf = 0;
  for (int T = w; T < PAIRS / 16; T += 48) {
    int P0 = T * 16;
    // stage h2 tile (16 pairs x 128 ch, bf16)
    int pr = P0 + pm;
    int n = pr / 20;
    int j = idxB[pr] & (NPTS - 1);   // mask: a sentinel index can never wild-read
    const uint4 P4 = *(const uint4*)(pB + (size_t)j * 128 + cseg * 8);
    const uint4 Q4 = *(const uint4*)(qB + (size_t)n * 128 + cseg * 8);
    uint4 R;
    R.x = pair_h2(P4.x, Q4.x);
    R.y = pair_h2(P4.y, Q4.y);
    R.z = pair_h2(P4.z, Q4.z);
    R.w = pair_h2(P4.w, Q4.w);
    *(uint4*)&h2s[buf][pm * 136 + cseg * 8] = R;
    __syncthreads();

    // A fragments: A[m=lane&15][k=quad*8+j]
    v8s a[4];
#pragma unroll
    for (int kk = 0; kk < 4; ++kk)
      a[kk] = *(const v8s*)&h2s[buf][r16 * 136 + kk * 32 + quad * 8];

#pragma unroll
    for (int ntl = 0; ntl < 4; ++ntl) {
      v4f acc = {0.f, 0.f, 0.f, 0.f};
#pragma unroll
      for (int kk = 0; kk < 4; ++kk)
        acc = __builtin_amdgcn_mfma_f32_16x16x32_bf16(a[kk], bfr[ntl][kk], acc, 0, 0, 0);
      // relu folds into max (vmx starts at 0); acc rows = pairs, col = channel
      vmx[ntl] = fmaxf(vmx[ntl], fmaxf(fmaxf(acc[0], acc[1]), fmaxf(acc[2], acc[3])));
    }
    buf ^= 1;
  }

  // reduce across quads (rows are pairs -> max over all), then global atomicMax
#pragma unroll
  for (int ntl = 0; ntl < 4; ++ntl) {
    float vv = vmx[ntl];
    vv = fmaxf(vv, __shfl_xor(vv, 16));
    vv = fmaxf(vv, __shfl_xor(vv, 32));
    if (quad == 0) {
      int ch = (wid * 4 + ntl) * 16 + r16;
      atomicMax(&H[b * 256 + ch], __float_as_int(vv));  // values >= 0: int order == float order
    }
  }
}

// ---------- K4: out = H @ fc_w^T + fc_b ----------
__global__ void fc_kernel(const int* __restrict__ Hi, const float* __restrict__ fcw,
                          const float* __restrict__ fcb, float* __restrict__ out) {
  int t = threadIdx.x;
  if (t >= BATCH * 10) return;
  int b = t / 10, r = t % 10;
  const float* Hb = (const float*)Hi + b * 256;
  float s = fcb[r];
  for (int c = 0; c < 256; ++c) s += Hb[c] * fcw[r * 256 + c];
  out[b * 10 + r] = s;
}

// ---------- launch ----------
extern "C" void kernel_launch(void* const* d_in, const int* in_sizes, int n_in,
                              void* d_out, int out_size, void* d_ws, size_t ws_size,
                              hipStream_t stream) {
  const float* x   = (const float*)d_in[0];
  const float* W1  = (const float*)d_in[1];
  const float* W2  = (const float*)d_in[2];
  const float* W3  = (const float*)d_in[3];
  const float* fcw = (const float*)d_in[4];
  const float* fcb = (const float*)d_in[5];
  float* out = (float*)d_out;
  char* ws = (char*)d_ws;

  // workspace layout (needs ~20 MB)
  float* M2a = (float*)(ws + 0);            // 1536 B
  float* M2b = (float*)(ws + 1536);         // 1536 B
  int* H     = (int*)(ws + 4096);           // 16 KB (16x256 f32-as-int)
  int* idx   = (int*)(ws + 24576);          // 2.62 MB
  unsigned short* p = (unsigned short*)(ws + 3145728);   // 8.39 MB bf16
  unsigned short* q = (unsigned short*)(ws + 12582912);  // 8.39 MB bf16

  prep_kernel<<<32, 128, 0, stream>>>(W1, W2, M2a, M2b, H);
  pq_kernel<<<BATCH * 64, 64, 0, stream>>>(x, M2a, M2b, p, q);
  knn_kernel<<<BATCH * 512, 256, 0, stream>>>(x, idx);
  gemm_max_kernel<<<BATCH * 48, 256, 0, stream>>>(p, q, idx, W3, H);
  fc_kernel<<<1, 256, 0, stream>>>(H, fcw, fcb, out);
}

// Round 4
// 197.241 us; speedup vs baseline: 1.2466x; 1.2466x over previous
//
#include <hip/hip_runtime.h>
#include <stdint.h>

typedef short v8s __attribute__((ext_vector_type(8)));
typedef float v4f __attribute__((ext_vector_type(4)));

#define NPTS 2048
#define BATCH 16
#define KNN 20
#define PAIRS (NPTS * KNN)   // 40960 per batch

// ---------- helpers ----------
__device__ __forceinline__ unsigned bf16pack2(float lo, float hi) {
  unsigned ul = __float_as_uint(lo), uh = __float_as_uint(hi);
  return ((ul + 0x8000u) >> 16) | ((uh + 0x8000u) & 0xffff0000u);
}
__device__ __forceinline__ unsigned pair_h2(unsigned pu, unsigned qu) {
  float pl = __uint_as_float(pu << 16);
  float ph = __uint_as_float(pu & 0xffff0000u);
  float ql = __uint_as_float(qu << 16);
  float qh = __uint_as_float(qu & 0xffff0000u);
  return bf16pack2(fmaxf(pl + ql, 0.f), fmaxf(ph + qh, 0.f));
}

// ---------- K0: fold M2a = W2*W1a, M2b = W2*(W1b-W1a); zero H ----------
__global__ void prep_kernel(const float* __restrict__ W1, const float* __restrict__ W2,
                            float* __restrict__ M2a, float* __restrict__ M2b,
                            int* __restrict__ H) {
  if (blockIdx.x == 0 && threadIdx.x < 128) {
    int o = threadIdx.x;
    float a0 = 0, a1 = 0, a2 = 0, b0 = 0, b1 = 0, b2 = 0;
    for (int i = 0; i < 64; ++i) {
      float w2 = W2[o * 64 + i];
      const float* w1r = W1 + i * 6;
      a0 += w2 * w1r[0]; a1 += w2 * w1r[1]; a2 += w2 * w1r[2];
      b0 += w2 * (w1r[3] - w1r[0]); b1 += w2 * (w1r[4] - w1r[1]); b2 += w2 * (w1r[5] - w1r[2]);
    }
    M2a[o * 3 + 0] = a0; M2a[o * 3 + 1] = a1; M2a[o * 3 + 2] = a2;
    M2b[o * 3 + 0] = b0; M2b[o * 3 + 1] = b1; M2b[o * 3 + 2] = b2;
  }
  int g = blockIdx.x * 128 + threadIdx.x;
  if (g < BATCH * 256) H[g] = 0;
}

// ---------- K1: p[b][j][o] = M2a[o]·x_j ; q likewise (bf16, packed pairs) ----------
__global__ __launch_bounds__(64) void pq_kernel(const float* __restrict__ x,
                                                const float* __restrict__ M2a,
                                                const float* __restrict__ M2b,
                                                unsigned short* __restrict__ p,
                                                unsigned short* __restrict__ q) {
  int b = blockIdx.x >> 6;
  int j0 = (blockIdx.x & 63) << 5;
  int t = threadIdx.x;                 // 0..63 -> channels 2t, 2t+1
  int o0 = t * 2;
  float a00 = M2a[o0 * 3 + 0], a01 = M2a[o0 * 3 + 1], a02 = M2a[o0 * 3 + 2];
  float a10 = M2a[o0 * 3 + 3], a11 = M2a[o0 * 3 + 4], a12 = M2a[o0 * 3 + 5];
  float b00 = M2b[o0 * 3 + 0], b01 = M2b[o0 * 3 + 1], b02 = M2b[o0 * 3 + 2];
  float b10 = M2b[o0 * 3 + 3], b11 = M2b[o0 * 3 + 4], b12 = M2b[o0 * 3 + 5];
  const float* xb = x + b * 3 * NPTS;
  unsigned* pw = (unsigned*)p;
  unsigned* qw = (unsigned*)q;
  for (int jj = 0; jj < 32; ++jj) {
    int j = j0 + jj;
    float x0 = xb[j], x1 = xb[NPTS + j], x2 = xb[2 * NPTS + j];
    float p0 = a00 * x0 + a01 * x1 + a02 * x2;
    float p1 = a10 * x0 + a11 * x1 + a12 * x2;
    float q0 = b00 * x0 + b01 * x1 + b02 * x2;
    float q1 = b10 * x0 + b11 * x1 + b12 * x2;
    size_t base = ((size_t)(b * NPTS + j)) * 64 + t;   // dword index
    pw[base] = bf16pack2(p0, p1);
    qw[base] = bf16pack2(q0, q1);
  }
}

// ---------- K2: exact 20-NN, one wave per query ----------
// R3 post-mortem: LDS-pipe-bound, NOT VALU-bound. float4 pts[] = stride-16B =
// 8-way bank conflict on every ds_read_b128 (196k conflicts); bitonic-128 on
// 64-bit keys = ~108 ds_swizzle ops (LDS pipe too). R4: (1) SoA px/py/pz
// (stride 4B, 2-way = free) kills conflicts, LDS 36.9->28KB lifts occupancy
// 40->62%; (2) rank-count select via broadcast ds_read_b64 (~nc~25 ops)
// replaces bitonic-128 (~108 swizzles). Keys unique (index tiebreak) -> exact.
__global__ __launch_bounds__(256) void knn_kernel(const float* __restrict__ x,
                                                  int* __restrict__ idxOut) {
  __shared__ float px[NPTS], py[NPTS], pz[NPTS];      // 24 KB, conflict-free
  __shared__ unsigned long long cand[4][128];         // 4 KB candidate keys
  int b = blockIdx.x >> 9;
  int qb = (blockIdx.x & 511) << 2;
  const float* xb = x + b * 3 * NPTS;
  for (int i = threadIdx.x; i < NPTS; i += 256) {
    px[i] = xb[i]; py[i] = xb[NPTS + i]; pz[i] = xb[2 * NPTS + i];
  }
  __syncthreads();
  int wid = threadIdx.x >> 6, lane = threadIdx.x & 63;
  int qn = qb + wid;
  float qx = px[qn], qy = py[qn], qz = pz[qn];   // broadcast reads

  // pass 1: per-lane min distance over its 32 points
  float mymin = 1e30f;
#pragma unroll
  for (int s = 0; s < 32; ++s) {
    int i = s * 64 + lane;
    float dx = px[i] - qx, dy = py[i] - qy, dz = pz[i] - qz;
    float d = dx * dx + dy * dy + dz * dz;
    mymin = fminf(mymin, d);
  }
  // bitonic sort 64 lane-minima ascending -> tau = 20th smallest.
  // The 20 smallest lane-minima are 20 actual distances in distinct lanes,
  // all <= tau => d_(20) <= tau.
  float v = mymin;
  for (int k = 2; k <= 64; k <<= 1) {
    for (int j = k >> 1; j > 0; j >>= 1) {
      float o = __shfl_xor(v, j);
      bool low = (lane & j) == 0;
      bool up = (lane & k) == 0;
      v = (low == up) ? fminf(v, o) : fmaxf(v, o);
    }
  }
  float tau = __shfl(v, 19);
  tau = tau * (1.0f + 3.8e-6f);   // +2^-18 rel: covers cross-pass FMA-contraction ulps

  // pass 2: recompute distances, ballot-compact candidates with d <= tau
  int base = 0;
#pragma unroll
  for (int s = 0; s < 32; ++s) {
    int i = s * 64 + lane;
    float dx = px[i] - qx, dy = py[i] - qy, dz = pz[i] - qz;
    float d = dx * dx + dy * dy + dz * dz;
    bool take = d <= tau;
    unsigned long long mb = __ballot(take);
    if (take) {
      int pos = base + __popcll(mb & ((1ull << lane) - 1ull));
      if (pos < 128)
        cand[wid][pos] = (((unsigned long long)__float_as_uint(d)) << 32) | (unsigned)i;
    }
    base += __popcll(mb);
  }
  int nc = base < 128 ? base : 128;
  __syncthreads();

  // rank-count select: each lane owns <=2 keys; rank = #{keys < mine} via
  // broadcast reads (same addr across lanes = free). rank < 20 -> winner,
  // written to output slot `rank` (distance-ascending order preserved).
  unsigned long long k0 = (lane < nc) ? cand[wid][lane] : ~0ull;
  unsigned long long k1 = (lane + 64 < nc) ? cand[wid][lane + 64] : ~0ull;
  int r0 = 0, r1 = 0;
  for (int i = 0; i < nc; ++i) {
    unsigned long long ki = cand[wid][i];
    r0 += (ki < k0) ? 1 : 0;
    r1 += (ki < k1) ? 1 : 0;
  }
  long long obase = ((long long)b * NPTS + qn) * KNN;
  if (lane < nc && r0 < KNN) idxOut[obase + r0] = (int)(k0 & 0xffffffffu);
  if (lane + 64 < nc && r1 < KNN) idxOut[obase + r1] = (int)(k1 & 0xffffffffu);
}

// ---------- K3: h3 = relu(W3 · relu(p_j+q_n)) via MFMA, fused max-reduce ----------
// R4: software-pipeline the gathers — prefetch next tile's idx + p/q right
// after the barrier so the ~200-400cy L2 gather latency hides behind MFMA.
__global__ __launch_bounds__(256, 2) void gemm_max_kernel(
    const unsigned short* __restrict__ p, const unsigned short* __restrict__ q,
    const int* __restrict__ idx, const float* __restrict__ W3, int* __restrict__ H) {
  __shared__ __align__(16) unsigned short h2s[2][16 * 136];  // 8704 B double-buffered tile

  int b = blockIdx.x & 15;
  int w = blockIdx.x >> 4;  // 0..47
  int t = threadIdx.x;
  int lane = t & 63, wid = t >> 6;
  int r16 = lane & 15, quad = lane >> 4;

  // Preload all B fragments (W3^T rows, bf16) into registers: 4 ntiles x 4 ksteps
  v8s bfr[4][4];
#pragma unroll
  for (int ntl = 0; ntl < 4; ++ntl) {
#pragma unroll
    for (int kk = 0; kk < 4; ++kk) {
      int n = (wid * 4 + ntl) * 16 + r16;
      const float* src = W3 + n * 128 + kk * 32 + quad * 8;
      v8s f;
#pragma unroll
      for (int jj = 0; jj < 8; ++jj)
        f[jj] = (short)((__float_as_uint(src[jj]) + 0x8000u) >> 16);
      bfr[ntl][kk] = f;
    }
  }

  const unsigned short* pB = p + (size_t)b * NPTS * 128;
  const unsigned short* qB = q + (size_t)b * NPTS * 128;
  const int* idxB = idx + (size_t)b * PAIRS;

  int pm = t >> 4;        // pair-in-tile 0..15
  int cseg = t & 15;      // 8-channel segment

  // prologue prefetch for first tile
  uint4 P4n, Q4n;
  {
    int pr = w * 16 + pm;
    int n0 = pr / 20;
    int j0 = idxB[pr] & (NPTS - 1);
    P4n = *(const uint4*)(pB + (size_t)j0 * 128 + cseg * 8);
    Q4n = *(const uint4*)(qB + (size_t)n0 * 128 + cseg * 8);
  }

  float vmx[4] = {0.f, 0.f, 0.f, 0.f};
  int buf = 0;
  for (int T = w; T < PAIRS / 16; T += 48) {
    // stage h2 tile (16 pairs x 128 ch, bf16) from prefetched regs
    uint4 R;
    R.x = pair_h2(P4n.x, Q4n.x);
    R.y = pair_h2(P4n.y, Q4n.y);
    R.z = pair_h2(P4n.z, Q4n.z);
    R.w = pair_h2(P4n.w, Q4n.w);
    *(uint4*)&h2s[buf][pm * 136 + cseg * 8] = R;
    __syncthreads();

    // prefetch next tile (consumed next iteration; latency hidden by MFMA)
    int Tn = T + 48;
    if (Tn < PAIRS / 16) {
      int prn = Tn * 16 + pm;
      int nn = prn / 20;
      int jn = idxB[prn] & (NPTS - 1);
      P4n = *(const uint4*)(pB + (size_t)jn * 128 + cseg * 8);
      Q4n = *(const uint4*)(qB + (size_t)nn * 128 + cseg * 8);
    }

    // A fragments: A[m=lane&15][k=quad*8+j]
    v8s a[4];
#pragma unroll
    for (int kk = 0; kk < 4; ++kk)
      a[kk] = *(const v8s*)&h2s[buf][r16 * 136 + kk * 32 + quad * 8];

#pragma unroll
    for (int ntl = 0; ntl < 4; ++ntl) {
      v4f acc = {0.f, 0.f, 0.f, 0.f};
#pragma unroll
      for (int kk = 0; kk < 4; ++kk)
        acc = __builtin_amdgcn_mfma_f32_16x16x32_bf16(a[kk], bfr[ntl][kk], acc, 0, 0, 0);
      // relu folds into max (vmx starts at 0); acc rows = pairs, col = channel
      vmx[ntl] = fmaxf(vmx[ntl], fmaxf(fmaxf(acc[0], acc[1]), fmaxf(acc[2], acc[3])));
    }
    buf ^= 1;
  }

  // reduce across quads (rows are pairs -> max over all), then global atomicMax
#pragma unroll
  for (int ntl = 0; ntl < 4; ++ntl) {
    float vv = vmx[ntl];
    vv = fmaxf(vv, __shfl_xor(vv, 16));
    vv = fmaxf(vv, __shfl_xor(vv, 32));
    if (quad == 0) {
      int ch = (wid * 4 + ntl) * 16 + r16;
      atomicMax(&H[b * 256 + ch], __float_as_int(vv));  // values >= 0: int order == float order
    }
  }
}

// ---------- K4: out = H @ fc_w^T + fc_b ----------
__global__ void fc_kernel(const int* __restrict__ Hi, const float* __restrict__ fcw,
                          const float* __restrict__ fcb, float* __restrict__ out) {
  int t = threadIdx.x;
  if (t >= BATCH * 10) return;
  int b = t / 10, r = t % 10;
  const float* Hb = (const float*)Hi + b * 256;
  float s = fcb[r];
  for (int c = 0; c < 256; ++c) s += Hb[c] * fcw[r * 256 + c];
  out[b * 10 + r] = s;
}

// ---------- launch ----------
extern "C" void kernel_launch(void* const* d_in, const int* in_sizes, int n_in,
                              void* d_out, int out_size, void* d_ws, size_t ws_size,
                              hipStream_t stream) {
  const float* x   = (const float*)d_in[0];
  const float* W1  = (const float*)d_in[1];
  const float* W2  = (const float*)d_in[2];
  const float* W3  = (const float*)d_in[3];
  const float* fcw = (const float*)d_in[4];
  const float* fcb = (const float*)d_in[5];
  float* out = (float*)d_out;
  char* ws = (char*)d_ws;

  // workspace layout (needs ~20 MB)
  float* M2a = (float*)(ws + 0);            // 1536 B
  float* M2b = (float*)(ws + 1536);         // 1536 B
  int* H     = (int*)(ws + 4096);           // 16 KB (16x256 f32-as-int)
  int* idx   = (int*)(ws + 24576);          // 2.62 MB
  unsigned short* p = (unsigned short*)(ws + 3145728);   // 8.39 MB bf16
  unsigned short* q = (unsigned short*)(ws + 12582912);  // 8.39 MB bf16

  prep_kernel<<<32, 128, 0, stream>>>(W1, W2, M2a, M2b, H);
  pq_kernel<<<BATCH * 64, 64, 0, stream>>>(x, M2a, M2b, p, q);
  knn_kernel<<<BATCH * 512, 256, 0, stream>>>(x, idx);
  gemm_max_kernel<<<BATCH * 48, 256, 0, stream>>>(p, q, idx, W3, H);
  fc_kernel<<<1, 256, 0, stream>>>(H, fcw, fcb, out);
}

// Round 5
// 192.810 us; speedup vs baseline: 1.2753x; 1.0230x over previous
//
#include <hip/hip_runtime.h>
#include <stdint.h>

typedef short v8s __attribute__((ext_vector_type(8)));
typedef float v4f __attribute__((ext_vector_type(4)));

#define NPTS 2048
#define BATCH 16
#define KNN 20
#define PAIRS (NPTS * KNN)   // 40960 per batch

// ---------- helpers ----------
__device__ __forceinline__ unsigned bf16pack2(float lo, float hi) {
  unsigned ul = __float_as_uint(lo), uh = __float_as_uint(hi);
  return ((ul + 0x8000u) >> 16) | ((uh + 0x8000u) & 0xffff0000u);
}
__device__ __forceinline__ unsigned pair_h2(unsigned pu, unsigned qu) {
  float pl = __uint_as_float(pu << 16);
  float ph = __uint_as_float(pu & 0xffff0000u);
  float ql = __uint_as_float(qu << 16);
  float qh = __uint_as_float(qu & 0xffff0000u);
  return bf16pack2(fmaxf(pl + ql, 0.f), fmaxf(ph + qh, 0.f));
}

// ---------- K0: fold M2a = W2*W1a, M2b = W2*(W1b-W1a); zero H ----------
__global__ void prep_kernel(const float* __restrict__ W1, const float* __restrict__ W2,
                            float* __restrict__ M2a, float* __restrict__ M2b,
                            int* __restrict__ H) {
  if (blockIdx.x == 0 && threadIdx.x < 128) {
    int o = threadIdx.x;
    float a0 = 0, a1 = 0, a2 = 0, b0 = 0, b1 = 0, b2 = 0;
    for (int i = 0; i < 64; ++i) {
      float w2 = W2[o * 64 + i];
      const float* w1r = W1 + i * 6;
      a0 += w2 * w1r[0]; a1 += w2 * w1r[1]; a2 += w2 * w1r[2];
      b0 += w2 * (w1r[3] - w1r[0]); b1 += w2 * (w1r[4] - w1r[1]); b2 += w2 * (w1r[5] - w1r[2]);
    }
    M2a[o * 3 + 0] = a0; M2a[o * 3 + 1] = a1; M2a[o * 3 + 2] = a2;
    M2b[o * 3 + 0] = b0; M2b[o * 3 + 1] = b1; M2b[o * 3 + 2] = b2;
  }
  int g = blockIdx.x * 128 + threadIdx.x;
  if (g < BATCH * 256) H[g] = 0;
}

// ---------- K1: p[b][j][o] = M2a[o]·x_j ; q likewise (bf16, packed pairs) ----------
__global__ __launch_bounds__(64) void pq_kernel(const float* __restrict__ x,
                                                const float* __restrict__ M2a,
                                                const float* __restrict__ M2b,
                                                unsigned short* __restrict__ p,
                                                unsigned short* __restrict__ q) {
  int b = blockIdx.x >> 6;
  int j0 = (blockIdx.x & 63) << 5;
  int t = threadIdx.x;                 // 0..63 -> channels 2t, 2t+1
  int o0 = t * 2;
  float a00 = M2a[o0 * 3 + 0], a01 = M2a[o0 * 3 + 1], a02 = M2a[o0 * 3 + 2];
  float a10 = M2a[o0 * 3 + 3], a11 = M2a[o0 * 3 + 4], a12 = M2a[o0 * 3 + 5];
  float b00 = M2b[o0 * 3 + 0], b01 = M2b[o0 * 3 + 1], b02 = M2b[o0 * 3 + 2];
  float b10 = M2b[o0 * 3 + 3], b11 = M2b[o0 * 3 + 4], b12 = M2b[o0 * 3 + 5];
  const float* xb = x + b * 3 * NPTS;
  unsigned* pw = (unsigned*)p;
  unsigned* qw = (unsigned*)q;
  for (int jj = 0; jj < 32; ++jj) {
    int j = j0 + jj;
    float x0 = xb[j], x1 = xb[NPTS + j], x2 = xb[2 * NPTS + j];
    float p0 = a00 * x0 + a01 * x1 + a02 * x2;
    float p1 = a10 * x0 + a11 * x1 + a12 * x2;
    float q0 = b00 * x0 + b01 * x1 + b02 * x2;
    float q1 = b10 * x0 + b11 * x1 + b12 * x2;
    size_t base = ((size_t)(b * NPTS + j)) * 64 + t;   // dword index
    pw[base] = bf16pack2(p0, p1);
    qw[base] = bf16pack2(q0, q1);
  }
}

// ---------- K2: exact 20-NN, 4 queries per wave ----------
// R4 post-mortem: per-query LDS traffic (49KB) over the 69 TB/s LDS pipe was
// the floor (~23us at 1 query/wave). R5: 4 queries/wave share each point read
// -> LDS traffic /4. cand[] is wave-private -> pass2 + select need NO barrier.
// tau inflation (2^-18) carried from R3 (cross-pass FMA-contraction ulps).
__global__ __launch_bounds__(256) void knn_kernel(const float* __restrict__ x,
                                                  int* __restrict__ idxOut) {
  __shared__ float px[NPTS], py[NPTS], pz[NPTS];      // 24 KB, stride-4B: conflict-free
  __shared__ unsigned long long cand[4][4][128];      // 16 KB, wave-private
  int b = blockIdx.x >> 7;
  int qblk = blockIdx.x & 127;
  const float* xb = x + b * 3 * NPTS;
  for (int i = threadIdx.x; i < NPTS; i += 256) {
    px[i] = xb[i]; py[i] = xb[NPTS + i]; pz[i] = xb[2 * NPTS + i];
  }
  __syncthreads();
  int wid = threadIdx.x >> 6, lane = threadIdx.x & 63;
  int qbase = qblk * 16 + wid * 4;                    // 4 queries per wave

  float qx[4], qy[4], qz[4], mn[4];
#pragma unroll
  for (int g = 0; g < 4; ++g) {
    qx[g] = px[qbase + g]; qy[g] = py[qbase + g]; qz[g] = pz[qbase + g];
    mn[g] = 1e30f;
  }

  // pass 1: per-lane min over its 32 points, for all 4 queries (shared loads)
  for (int s = 0; s < 32; ++s) {
    int i = s * 64 + lane;
    float X = px[i], Y = py[i], Z = pz[i];
#pragma unroll
    for (int g = 0; g < 4; ++g) {
      float dx = X - qx[g], dy = Y - qy[g], dz = Z - qz[g];
      mn[g] = fminf(mn[g], dx * dx + dy * dy + dz * dz);
    }
  }

  // tau[g] = 20th-smallest lane-min (upper bound on d_(20)), inflated
  float tau[4];
#pragma unroll
  for (int g = 0; g < 4; ++g) {
    float v = mn[g];
    for (int k = 2; k <= 64; k <<= 1) {
      for (int j = k >> 1; j > 0; j >>= 1) {
        float o = __shfl_xor(v, j);
        bool low = (lane & j) == 0;
        bool up = (lane & k) == 0;
        v = (low == up) ? fminf(v, o) : fmaxf(v, o);
      }
    }
    tau[g] = __shfl(v, 19) * (1.0f + 3.8e-6f);
  }

  // pass 2: recompute (shared loads), ballot-compact candidates per query
  int cnt[4] = {0, 0, 0, 0};
  for (int s = 0; s < 32; ++s) {
    int i = s * 64 + lane;
    float X = px[i], Y = py[i], Z = pz[i];
#pragma unroll
    for (int g = 0; g < 4; ++g) {
      float dx = X - qx[g], dy = Y - qy[g], dz = Z - qz[g];
      float d = dx * dx + dy * dy + dz * dz;
      bool take = d <= tau[g];
      unsigned long long mb = __ballot(take);
      if (take) {
        int pos = cnt[g] + __popcll(mb & ((1ull << lane) - 1ull));
        if (pos < 128)
          cand[wid][g][pos] =
              (((unsigned long long)__float_as_uint(d)) << 32) | (unsigned)i;
      }
      cnt[g] += __popcll(mb);
    }
  }
  // cand written & read by the same wave: no __syncthreads needed.

  // rank-count select per query: broadcast reads (same addr all lanes = free).
  // Keys unique (index tiebreak) -> exact ranks; winners rank<20 write slot rank.
#pragma unroll
  for (int g = 0; g < 4; ++g) {
    int nc = cnt[g] < 128 ? cnt[g] : 128;
    unsigned long long k0 = (lane < nc) ? cand[wid][g][lane] : ~0ull;
    unsigned long long k1 = (lane + 64 < nc) ? cand[wid][g][lane + 64] : ~0ull;
    int r0 = 0, r1 = 0;
    for (int i = 0; i < nc; ++i) {
      unsigned long long ki = cand[wid][g][i];
      r0 += (ki < k0) ? 1 : 0;
      r1 += (ki < k1) ? 1 : 0;
    }
    long long obase = ((long long)b * NPTS + qbase + g) * KNN;
    if (lane < nc && r0 < KNN) idxOut[obase + r0] = (int)(k0 & 0xffffffffu);
    if (lane + 64 < nc && r1 < KNN) idxOut[obase + r1] = (int)(k1 & 0xffffffffu);
  }
}

// ---------- K3: h3 = relu(W3 · relu(p_j+q_n)) via MFMA, fused max-reduce ----------
// R5: grid 768->1536 (6 blocks/CU at VGPR=80; R4 measured occupancy 28% with
// grid=3/CU as the cap). Structure unchanged (prefetch depth 1, 16-pair tile).
__global__ __launch_bounds__(256, 2) void gemm_max_kernel(
    const unsigned short* __restrict__ p, const unsigned short* __restrict__ q,
    const int* __restrict__ idx, const float* __restrict__ W3, int* __restrict__ H) {
  __shared__ __align__(16) unsigned short h2s[2][16 * 136];  // 8704 B double-buffered tile

  int b = blockIdx.x & 15;
  int w = blockIdx.x >> 4;  // 0..95
  int t = threadIdx.x;
  int lane = t & 63, wid = t >> 6;
  int r16 = lane & 15, quad = lane >> 4;

  // Preload all B fragments (W3^T rows, bf16) into registers: 4 ntiles x 4 ksteps
  v8s bfr[4][4];
#pragma unroll
  for (int ntl = 0; ntl < 4; ++ntl) {
#pragma unroll
    for (int kk = 0; kk < 4; ++kk) {
      int n = (wid * 4 + ntl) * 16 + r16;
      const float* src = W3 + n * 128 + kk * 32 + quad * 8;
      v8s f;
#pragma unroll
      for (int jj = 0; jj < 8; ++jj)
        f[jj] = (short)((__float_as_uint(src[jj]) + 0x8000u) >> 16);
      bfr[ntl][kk] = f;
    }
  }

  const unsigned short* pB = p + (size_t)b * NPTS * 128;
  const unsigned short* qB = q + (size_t)b * NPTS * 128;
  const int* idxB = idx + (size_t)b * PAIRS;

  int pm = t >> 4;        // pair-in-tile 0..15
  int cseg = t & 15;      // 8-channel segment

  // prologue prefetch for first tile
  uint4 P4n, Q4n;
  {
    int pr = w * 16 + pm;
    int n0 = pr / 20;
    int j0 = idxB[pr] & (NPTS - 1);
    P4n = *(const uint4*)(pB + (size_t)j0 * 128 + cseg * 8);
    Q4n = *(const uint4*)(qB + (size_t)n0 * 128 + cseg * 8);
  }

  float vmx[4] = {0.f, 0.f, 0.f, 0.f};
  int buf = 0;
  for (int T = w; T < PAIRS / 16; T += 96) {
    // stage h2 tile (16 pairs x 128 ch, bf16) from prefetched regs
    uint4 R;
    R.x = pair_h2(P4n.x, Q4n.x);
    R.y = pair_h2(P4n.y, Q4n.y);
    R.z = pair_h2(P4n.z, Q4n.z);
    R.w = pair_h2(P4n.w, Q4n.w);
    *(uint4*)&h2s[buf][pm * 136 + cseg * 8] = R;
    __syncthreads();

    // prefetch next tile (consumed next iteration; latency hidden by MFMA)
    int Tn = T + 96;
    if (Tn < PAIRS / 16) {
      int prn = Tn * 16 + pm;
      int nn = prn / 20;
      int jn = idxB[prn] & (NPTS - 1);
      P4n = *(const uint4*)(pB + (size_t)jn * 128 + cseg * 8);
      Q4n = *(const uint4*)(qB + (size_t)nn * 128 + cseg * 8);
    }

    // A fragments: A[m=lane&15][k=quad*8+j]
    v8s a[4];
#pragma unroll
    for (int kk = 0; kk < 4; ++kk)
      a[kk] = *(const v8s*)&h2s[buf][r16 * 136 + kk * 32 + quad * 8];

#pragma unroll
    for (int ntl = 0; ntl < 4; ++ntl) {
      v4f acc = {0.f, 0.f, 0.f, 0.f};
#pragma unroll
      for (int kk = 0; kk < 4; ++kk)
        acc = __builtin_amdgcn_mfma_f32_16x16x32_bf16(a[kk], bfr[ntl][kk], acc, 0, 0, 0);
      // relu folds into max (vmx starts at 0); acc rows = pairs, col = channel
      vmx[ntl] = fmaxf(vmx[ntl], fmaxf(fmaxf(acc[0], acc[1]), fmaxf(acc[2], acc[3])));
    }
    buf ^= 1;
  }

  // reduce across quads (rows are pairs -> max over all), then global atomicMax
#pragma unroll
  for (int ntl = 0; ntl < 4; ++ntl) {
    float vv = vmx[ntl];
    vv = fmaxf(vv, __shfl_xor(vv, 16));
    vv = fmaxf(vv, __shfl_xor(vv, 32));
    if (quad == 0) {
      int ch = (wid * 4 + ntl) * 16 + r16;
      atomicMax(&H[b * 256 + ch], __float_as_int(vv));  // values >= 0: int order == float order
    }
  }
}

// ---------- K4: out = H @ fc_w^T + fc_b (one wave per output element) ----------
__global__ __launch_bounds__(64) void fc_kernel(const int* __restrict__ Hi,
                                                const float* __restrict__ fcw,
                                                const float* __restrict__ fcb,
                                                float* __restrict__ out) {
  int b = blockIdx.x / 10, r = blockIdx.x % 10;
  int lane = threadIdx.x;
  const float* Hb = (const float*)Hi + b * 256;
  float s = 0.f;
#pragma unroll
  for (int c = lane; c < 256; c += 64) s += Hb[c] * fcw[r * 256 + c];
#pragma unroll
  for (int m = 32; m > 0; m >>= 1) s += __shfl_xor(s, m);
  if (lane == 0) out[b * 10 + r] = s + fcb[r];
}

// ---------- launch ----------
extern "C" void kernel_launch(void* const* d_in, const int* in_sizes, int n_in,
                              void* d_out, int out_size, void* d_ws, size_t ws_size,
                              hipStream_t stream) {
  const float* x   = (const float*)d_in[0];
  const float* W1  = (const float*)d_in[1];
  const float* W2  = (const float*)d_in[2];
  const float* W3  = (const float*)d_in[3];
  const float* fcw = (const float*)d_in[4];
  const float* fcb = (const float*)d_in[5];
  float* out = (float*)d_out;
  char* ws = (char*)d_ws;

  // workspace layout (needs ~20 MB)
  float* M2a = (float*)(ws + 0);            // 1536 B
  float* M2b = (float*)(ws + 1536);         // 1536 B
  int* H     = (int*)(ws + 4096);           // 16 KB (16x256 f32-as-int)
  int* idx   = (int*)(ws + 24576);          // 2.62 MB
  unsigned short* p = (unsigned short*)(ws + 3145728);   // 8.39 MB bf16
  unsigned short* q = (unsigned short*)(ws + 12582912);  // 8.39 MB bf16

  prep_kernel<<<32, 128, 0, stream>>>(W1, W2, M2a, M2b, H);
  pq_kernel<<<BATCH * 64, 64, 0, stream>>>(x, M2a, M2b, p, q);
  knn_kernel<<<BATCH * 128, 256, 0, stream>>>(x, idx);
  gemm_max_kernel<<<BATCH * 96, 256, 0, stream>>>(p, q, idx, W3, H);
  fc_kernel<<<BATCH * 10, 64, 0, stream>>>(H, fcw, fcb, out);
}